// Round 1
// baseline (1436.952 us; speedup 1.0000x reference)
//
#include <hip/hip_runtime.h>

#define N_NODES 100000
#define N_EDGES 1600000
#define DIN 128
#define NH 4
#define ND 32
#define HD 128   // NH*ND
#define NEG_SLOPE 0.2f

// ---- order-preserving float<->uint encoding for atomicMax on floats ----
__device__ __forceinline__ unsigned int enc_f32(float f) {
    unsigned int b = __float_as_uint(f);
    return (b & 0x80000000u) ? ~b : (b | 0x80000000u);
}
__device__ __forceinline__ float dec_f32(unsigned int u) {
    unsigned int b = (u & 0x80000000u) ? (u ^ 0x80000000u) : ~u;
    return __uint_as_float(b);
}
// enc_f32(-inf) = ~0xFF800000 = 0x007FFFFF
#define ENC_NEG_INF 0x007FFFFFu

__device__ __forceinline__ float lrelu(float x) {
    return x > 0.0f ? x : NEG_SLOPE * x;
}

// ---------------- init: zero out + denom, set emax to -inf ----------------
__global__ void k_init(float* __restrict__ out, float* __restrict__ denom,
                       unsigned int* __restrict__ emax) {
    int stride = gridDim.x * blockDim.x;
    for (int i = blockIdx.x * blockDim.x + threadIdx.x; i < N_NODES * HD; i += stride)
        out[i] = 0.0f;
    for (int i = blockIdx.x * blockDim.x + threadIdx.x; i < N_NODES * NH; i += stride) {
        denom[i] = 0.0f;
        emax[i] = ENC_NEG_INF;
    }
}

// ---------------- GEMM h = feat @ W, fused el/er reductions ----------------
// block = 256 threads. Each block computes 16 rows x 128 cols.
// thread: c = tid&127 (output column), half = tid>>7 selects rows [half*8, half*8+8)
#define GEMM_ROWS 16
__global__ __launch_bounds__(256) void k_gemm(
    const float* __restrict__ feat, const float* __restrict__ W,
    const float* __restrict__ attn_l, const float* __restrict__ attn_r,
    float* __restrict__ h, float* __restrict__ el, float* __restrict__ er) {

    __shared__ float Ws[DIN * HD];          // 64 KB
    __shared__ float fs[GEMM_ROWS][DIN];    // 8 KB
    __shared__ float al[HD], ar[HD];        // 1 KB

    const int tid = threadIdx.x;
    for (int i = tid; i < DIN * HD; i += 256) Ws[i] = W[i];
    if (tid < HD) { al[tid] = attn_l[tid]; ar[tid] = attn_r[tid]; }

    const int c = tid & 127;
    const int half = tid >> 7;
    const int hh = c >> 5;

    const int row0 = blockIdx.x * GEMM_ROWS;

    // stage 16 feat rows
    __syncthreads();
    for (int i = tid; i < GEMM_ROWS * DIN; i += 256) {
        int r = i >> 7, k = i & 127;
        int row = row0 + r;
        fs[r][k] = (row < N_NODES) ? feat[(size_t)row * DIN + k] : 0.0f;
    }
    __syncthreads();

    float acc[8];
#pragma unroll
    for (int r = 0; r < 8; ++r) acc[r] = 0.0f;

    for (int k = 0; k < DIN; ++k) {
        float w = Ws[k * HD + c];
#pragma unroll
        for (int r = 0; r < 8; ++r)
            acc[r] = fmaf(fs[half * 8 + r][k], w, acc[r]);
    }

#pragma unroll
    for (int r = 0; r < 8; ++r) {
        int row = row0 + half * 8 + r;
        if (row < N_NODES) {
            h[(size_t)row * HD + c] = acc[r];
            float vl = acc[r] * al[c];
            float vr = acc[r] * ar[c];
#pragma unroll
            for (int off = 16; off >= 1; off >>= 1) {
                vl += __shfl_down(vl, off, 32);
                vr += __shfl_down(vr, off, 32);
            }
            if ((c & 31) == 0) {
                el[(size_t)row * NH + hh] = vl;
                er[(size_t)row * NH + hh] = vr;
            }
        }
    }
}

// ---------------- edge logits -> segment max (atomicMax on encoded) -------
__global__ __launch_bounds__(256) void k_edge_max(
    const int* __restrict__ src, const int* __restrict__ dst,
    const float* __restrict__ el, const float* __restrict__ er,
    unsigned int* __restrict__ emax) {
    int e = blockIdx.x * blockDim.x + threadIdx.x;
    if (e >= N_EDGES) return;
    int s = src[e], d = dst[e];
    float4 l = *(const float4*)(el + (size_t)s * NH);
    float4 r = *(const float4*)(er + (size_t)d * NH);
    float x0 = lrelu(l.x + r.x), x1 = lrelu(l.y + r.y);
    float x2 = lrelu(l.z + r.z), x3 = lrelu(l.w + r.w);
    unsigned int* em = emax + (size_t)d * NH;
    atomicMax(em + 0, enc_f32(x0));
    atomicMax(em + 1, enc_f32(x1));
    atomicMax(em + 2, enc_f32(x2));
    atomicMax(em + 3, enc_f32(x3));
}

// ---------------- edge exp -> segment sum (denominator) -------------------
__global__ __launch_bounds__(256) void k_edge_denom(
    const int* __restrict__ src, const int* __restrict__ dst,
    const float* __restrict__ el, const float* __restrict__ er,
    const unsigned int* __restrict__ emax, float* __restrict__ denom) {
    int e = blockIdx.x * blockDim.x + threadIdx.x;
    if (e >= N_EDGES) return;
    int s = src[e], d = dst[e];
    float4 l = *(const float4*)(el + (size_t)s * NH);
    float4 r = *(const float4*)(er + (size_t)d * NH);
    const unsigned int* em = emax + (size_t)d * NH;
    float* dn = denom + (size_t)d * NH;
    atomicAdd(dn + 0, __expf(lrelu(l.x + r.x) - dec_f32(em[0])));
    atomicAdd(dn + 1, __expf(lrelu(l.y + r.y) - dec_f32(em[1])));
    atomicAdd(dn + 2, __expf(lrelu(l.z + r.z) - dec_f32(em[2])));
    atomicAdd(dn + 3, __expf(lrelu(l.w + r.w) - dec_f32(em[3])));
}

// ---------------- weighted scatter aggregation ----------------------------
// thread t handles (edge = t>>7, channel c = t&127); 64-lane wave = one edge's
// channels 0..63 or 64..127 -> coalesced h read, coalesced atomicAdd on out.
__global__ __launch_bounds__(256) void k_aggregate(
    const int* __restrict__ src, const int* __restrict__ dst,
    const float* __restrict__ el, const float* __restrict__ er,
    const unsigned int* __restrict__ emax, const float* __restrict__ denom,
    const float* __restrict__ h, float* __restrict__ out) {
    long long t = (long long)blockIdx.x * blockDim.x + threadIdx.x;
    if (t >= (long long)N_EDGES * HD) return;
    int e = (int)(t >> 7);
    int c = (int)(t & 127);
    int hh = c >> 5;
    int s = src[e], d = dst[e];
    float x = lrelu(el[(size_t)s * NH + hh] + er[(size_t)d * NH + hh]);
    float m = dec_f32(emax[(size_t)d * NH + hh]);
    float a = __expf(x - m) / denom[(size_t)d * NH + hh];
    atomicAdd(out + (size_t)d * HD + c, h[(size_t)s * HD + c] * a);
}

extern "C" void kernel_launch(void* const* d_in, const int* in_sizes, int n_in,
                              void* d_out, int out_size, void* d_ws, size_t ws_size,
                              hipStream_t stream) {
    const float* feat   = (const float*)d_in[0];
    const int*   src    = (const int*)d_in[1];
    const int*   dst    = (const int*)d_in[2];
    const float* W      = (const float*)d_in[3];
    const float* attn_l = (const float*)d_in[4];
    const float* attn_r = (const float*)d_in[5];
    float* out = (float*)d_out;

    // workspace layout (f32 elements)
    float* h  = (float*)d_ws;                             // N*HD     (51.2 MB)
    float* el = h + (size_t)N_NODES * HD;                 // N*NH
    float* er = el + (size_t)N_NODES * NH;                // N*NH
    unsigned int* emax = (unsigned int*)(er + (size_t)N_NODES * NH); // N*NH
    float* denom = (float*)(emax + (size_t)N_NODES * NH); // N*NH

    k_init<<<2048, 256, 0, stream>>>(out, denom, emax);

    k_gemm<<<(N_NODES + GEMM_ROWS - 1) / GEMM_ROWS, 256, 0, stream>>>(
        feat, W, attn_l, attn_r, h, el, er);

    int eb = (N_EDGES + 255) / 256;
    k_edge_max<<<eb, 256, 0, stream>>>(src, dst, el, er, emax);
    k_edge_denom<<<eb, 256, 0, stream>>>(src, dst, el, er, emax, denom);

    long long tot = (long long)N_EDGES * HD;
    int ab = (int)((tot + 255) / 256);
    k_aggregate<<<ab, 256, 0, stream>>>(src, dst, el, er, emax, denom, h, out);
}

// Round 2
// 678.821 us; speedup vs baseline: 2.1168x; 2.1168x over previous
//
#include <hip/hip_runtime.h>

#define N_NODES 100000
#define N_EDGES 1600000
#define DIN 128
#define NH 4
#define ND 32
#define HD 128   // NH*ND
#define NEG_SLOPE 0.2f
#define SCAN_NB 98   // ceil(N_NODES / 1024)

__device__ __forceinline__ float lrelu(float x) {
    return x > 0.0f ? x : NEG_SLOPE * x;
}

// ---------------- init (CSR path): zero denom + deg ----------------------
__global__ void k_init(float* __restrict__ denom, int* __restrict__ deg) {
    int i = blockIdx.x * blockDim.x + threadIdx.x;
    int stride = gridDim.x * blockDim.x;
    for (int j = i; j < N_NODES * NH; j += stride) denom[j] = 0.0f;
    for (int j = i; j < N_NODES; j += stride) deg[j] = 0;
}

// ---------------- init (fallback path): zero out + denom -----------------
__global__ void k_init_fb(float* __restrict__ out, float* __restrict__ denom) {
    int i = blockIdx.x * blockDim.x + threadIdx.x;
    int stride = gridDim.x * blockDim.x;
    for (int j = i; j < N_NODES * HD; j += stride) out[j] = 0.0f;
    for (int j = i; j < N_NODES * NH; j += stride) denom[j] = 0.0f;
}

// ---------------- GEMM h = feat @ W, fused el/er -------------------------
// block 256 threads, tile 32 rows x 128 cols, thread = 4 rows x 4 cols.
// Per k: 1x ds_read_b128 (W) + 4x broadcast b32 (feat) -> 16 FMAs.
#define GROWS 32
__global__ __launch_bounds__(256) void k_gemm(
    const float* __restrict__ feat, const float* __restrict__ W,
    const float* __restrict__ attn_l, const float* __restrict__ attn_r,
    float* __restrict__ h, float* __restrict__ el, float* __restrict__ er) {

    __shared__ float Ws[DIN * HD];      // 64 KB, [k][c]
    __shared__ float fs[GROWS * DIN];   // 16 KB, [r][k]

    const int tid = threadIdx.x;
    const int row0 = blockIdx.x * GROWS;

    {   // stage W: 4096 float4
        const float4* Wv = (const float4*)W;
        float4* Sv = (float4*)Ws;
#pragma unroll
        for (int it = 0; it < 16; ++it) Sv[tid + it * 256] = Wv[tid + it * 256];
    }
    {   // stage 32 feat rows: 1024 float4
        const float4* Fv = (const float4*)(feat + (size_t)row0 * DIN);
        float4* Sv = (float4*)fs;
#pragma unroll
        for (int it = 0; it < 4; ++it) Sv[tid + it * 256] = Fv[tid + it * 256];
    }
    __syncthreads();

    const int cg = tid & 31;   // cols 4*cg .. 4*cg+3
    const int rg = tid >> 5;   // rows 4*rg .. 4*rg+3

    float acc[4][4];
#pragma unroll
    for (int r = 0; r < 4; ++r)
#pragma unroll
        for (int c = 0; c < 4; ++c) acc[r][c] = 0.0f;

#pragma unroll 4
    for (int k = 0; k < DIN; ++k) {
        float4 w = *(const float4*)&Ws[k * HD + cg * 4];
#pragma unroll
        for (int r = 0; r < 4; ++r) {
            float f = fs[(rg * 4 + r) * DIN + k];
            acc[r][0] = fmaf(f, w.x, acc[r][0]);
            acc[r][1] = fmaf(f, w.y, acc[r][1]);
            acc[r][2] = fmaf(f, w.z, acc[r][2]);
            acc[r][3] = fmaf(f, w.w, acc[r][3]);
        }
    }

    const float4 alv = *(const float4*)(attn_l + cg * 4);
    const float4 arv = *(const float4*)(attn_r + cg * 4);
    const int head = cg >> 3;

#pragma unroll
    for (int r = 0; r < 4; ++r) {
        int row = row0 + rg * 4 + r;
        *(float4*)&h[(size_t)row * HD + cg * 4] =
            make_float4(acc[r][0], acc[r][1], acc[r][2], acc[r][3]);
        float vl = acc[r][0] * alv.x + acc[r][1] * alv.y +
                   acc[r][2] * alv.z + acc[r][3] * alv.w;
        float vr = acc[r][0] * arv.x + acc[r][1] * arv.y +
                   acc[r][2] * arv.z + acc[r][3] * arv.w;
        vl += __shfl_down(vl, 4, 64);
        vl += __shfl_down(vl, 2, 64);
        vl += __shfl_down(vl, 1, 64);
        vr += __shfl_down(vr, 4, 64);
        vr += __shfl_down(vr, 2, 64);
        vr += __shfl_down(vr, 1, 64);
        if ((cg & 7) == 0) {
            el[(size_t)row * NH + head] = vl;
            er[(size_t)row * NH + head] = vr;
        }
    }
}

// ---------------- denominator (+ degree count) ---------------------------
// No max-subtraction: |logits| <~ 1.5 by construction, exp() is safe and
// softmax is shift-invariant.
__global__ __launch_bounds__(256) void k_denom_count(
    const int* __restrict__ src, const int* __restrict__ dst,
    const float* __restrict__ el, const float* __restrict__ er,
    float* __restrict__ denom, int* __restrict__ deg) {
    int e = blockIdx.x * blockDim.x + threadIdx.x;
    if (e >= N_EDGES) return;
    int s = src[e], d = dst[e];
    float4 l = *(const float4*)(el + (size_t)s * NH);
    float4 r = *(const float4*)(er + (size_t)d * NH);
    float* dn = denom + (size_t)d * NH;
    atomicAdd(dn + 0, __expf(lrelu(l.x + r.x)));
    atomicAdd(dn + 1, __expf(lrelu(l.y + r.y)));
    atomicAdd(dn + 2, __expf(lrelu(l.z + r.z)));
    atomicAdd(dn + 3, __expf(lrelu(l.w + r.w)));
    if (deg) atomicAdd(deg + d, 1);
}

// ---------------- scan: deg -> rowptr (exclusive) ------------------------
__global__ __launch_bounds__(256) void k_scanA(const int* __restrict__ deg,
                                               int* __restrict__ bsum) {
    __shared__ int wsum[4];
    int b = blockIdx.x, tid = threadIdx.x;
    int base = b * 1024 + tid * 4;
    int s = 0;
#pragma unroll
    for (int j = 0; j < 4; ++j) {
        int i = base + j;
        if (i < N_NODES) s += deg[i];
    }
#pragma unroll
    for (int off = 32; off >= 1; off >>= 1) s += __shfl_down(s, off, 64);
    if ((tid & 63) == 0) wsum[tid >> 6] = s;
    __syncthreads();
    if (tid == 0) bsum[b] = wsum[0] + wsum[1] + wsum[2] + wsum[3];
}

__global__ __launch_bounds__(128) void k_scanB(const int* __restrict__ bsum,
                                               int* __restrict__ boff) {
    __shared__ int tmp[SCAN_NB];
    int tid = threadIdx.x;
    if (tid < SCAN_NB) tmp[tid] = bsum[tid];
    __syncthreads();
    if (tid == 0) {
        int acc = 0;
        for (int i = 0; i < SCAN_NB; ++i) { int v = tmp[i]; tmp[i] = acc; acc += v; }
    }
    __syncthreads();
    if (tid < SCAN_NB) boff[tid] = tmp[tid];
}

__global__ __launch_bounds__(256) void k_scanC(const int* __restrict__ deg,
                                               const int* __restrict__ boff,
                                               int* __restrict__ rowptr,
                                               int* __restrict__ cursor) {
    __shared__ int wtot[4];
    int b = blockIdx.x, tid = threadIdx.x;
    int base = b * 1024 + tid * 4;
    int d[4];
#pragma unroll
    for (int j = 0; j < 4; ++j) {
        int i = base + j;
        d[j] = (i < N_NODES) ? deg[i] : 0;
    }
    int tsum = d[0] + d[1] + d[2] + d[3];
    int lane = tid & 63;
    int v = tsum;
#pragma unroll
    for (int off = 1; off < 64; off <<= 1) {
        int t = __shfl_up(v, off, 64);
        if (lane >= off) v += t;
    }
    if (lane == 63) wtot[tid >> 6] = v;
    int texcl = v - tsum;
    __syncthreads();
    int woff = 0;
    for (int w = 0; w < (tid >> 6); ++w) woff += wtot[w];
    int pfx = boff[b] + woff + texcl;
#pragma unroll
    for (int j = 0; j < 4; ++j) {
        int i = base + j;
        if (i < N_NODES) { rowptr[i] = pfx; cursor[i] = pfx; }
        else if (i == N_NODES) { rowptr[i] = pfx; }
        pfx += d[j];
    }
}

// ---------------- scatter: sorted-by-dst (src, weight4) ------------------
__global__ __launch_bounds__(256) void k_scatter(
    const int* __restrict__ src, const int* __restrict__ dst,
    const float* __restrict__ el, const float* __restrict__ er,
    const float* __restrict__ denom, int* __restrict__ cursor,
    int* __restrict__ srcs, float4* __restrict__ aw) {
    int e = blockIdx.x * blockDim.x + threadIdx.x;
    if (e >= N_EDGES) return;
    int s = src[e], d = dst[e];
    float4 l = *(const float4*)(el + (size_t)s * NH);
    float4 r = *(const float4*)(er + (size_t)d * NH);
    float4 dn = *(const float4*)(denom + (size_t)d * NH);
    float4 w = make_float4(__expf(lrelu(l.x + r.x)) / dn.x,
                           __expf(lrelu(l.y + r.y)) / dn.y,
                           __expf(lrelu(l.z + r.z)) / dn.z,
                           __expf(lrelu(l.w + r.w)) / dn.w);
    int slot = atomicAdd(cursor + d, 1);
    srcs[slot] = s;
    aw[slot] = w;
}

// ---------------- CSR gather-aggregate: no atomics, out written once -----
// One 64-lane wave per dst node; lane covers 2 channels (float2).
__global__ __launch_bounds__(256) void k_agg_csr(
    const int* __restrict__ rowptr, const int* __restrict__ srcs,
    const float* __restrict__ aw, const float* __restrict__ h,
    float* __restrict__ out) {
    int node = blockIdx.x * 4 + (threadIdx.x >> 6);
    int lane = threadIdx.x & 63;
    int c2 = lane * 2;
    int hh = lane >> 4;
    int beg = rowptr[node], end = rowptr[node + 1];
    float a0 = 0.0f, a1 = 0.0f;
    int i = beg;
    for (; i + 2 <= end; i += 2) {
        int s0 = srcs[i], s1 = srcs[i + 1];
        float w0 = aw[(size_t)i * 4 + hh];
        float w1 = aw[(size_t)(i + 1) * 4 + hh];
        float2 h0 = *(const float2*)(h + (size_t)s0 * HD + c2);
        float2 h1 = *(const float2*)(h + (size_t)s1 * HD + c2);
        a0 = fmaf(h0.x, w0, a0); a1 = fmaf(h0.y, w0, a1);
        a0 = fmaf(h1.x, w1, a0); a1 = fmaf(h1.y, w1, a1);
    }
    if (i < end) {
        int s0 = srcs[i];
        float w0 = aw[(size_t)i * 4 + hh];
        float2 h0 = *(const float2*)(h + (size_t)s0 * HD + c2);
        a0 = fmaf(h0.x, w0, a0); a1 = fmaf(h0.y, w0, a1);
    }
    *(float2*)(out + (size_t)node * HD + c2) = make_float2(a0, a1);
}

// ---------------- fallback: atomic aggregate -----------------------------
__global__ __launch_bounds__(256) void k_agg_fb(
    const int* __restrict__ src, const int* __restrict__ dst,
    const float* __restrict__ el, const float* __restrict__ er,
    const float* __restrict__ denom, const float* __restrict__ h,
    float* __restrict__ out) {
    long long t = (long long)blockIdx.x * blockDim.x + threadIdx.x;
    if (t >= (long long)N_EDGES * HD) return;
    int e = (int)(t >> 7);
    int c = (int)(t & 127);
    int hh = c >> 5;
    int s = src[e], d = dst[e];
    float x = lrelu(el[(size_t)s * NH + hh] + er[(size_t)d * NH + hh]);
    float a = __expf(x) / denom[(size_t)d * NH + hh];
    atomicAdd(out + (size_t)d * HD + c, h[(size_t)s * HD + c] * a);
}

extern "C" void kernel_launch(void* const* d_in, const int* in_sizes, int n_in,
                              void* d_out, int out_size, void* d_ws, size_t ws_size,
                              hipStream_t stream) {
    const float* feat   = (const float*)d_in[0];
    const int*   src    = (const int*)d_in[1];
    const int*   dst    = (const int*)d_in[2];
    const float* W      = (const float*)d_in[3];
    const float* attn_l = (const float*)d_in[4];
    const float* attn_r = (const float*)d_in[5];
    float* out = (float*)d_out;

    char* base = (char*)d_ws;
    size_t off = 0;
    auto take = [&](size_t bytes) -> char* {
        char* r = base + off;
        off = (off + bytes + 255) & ~(size_t)255;
        return r;
    };
    float* h      = (float*)take((size_t)N_NODES * HD * 4);
    float* el     = (float*)take((size_t)N_NODES * NH * 4);
    float* er     = (float*)take((size_t)N_NODES * NH * 4);
    float* denom  = (float*)take((size_t)N_NODES * NH * 4);
    int*   deg    = (int*)take((size_t)N_NODES * 4);
    int*   rowptr = (int*)take((size_t)(N_NODES + 1) * 4);
    int*   cursor = (int*)take((size_t)N_NODES * 4);
    int*   bsum   = (int*)take(SCAN_NB * 4);
    int*   boff   = (int*)take(SCAN_NB * 4);
    int*   srcs   = (int*)take((size_t)N_EDGES * 4);
    float* aw     = (float*)take((size_t)N_EDGES * NH * 4);
    bool csr = (off <= ws_size);

    int eb = (N_EDGES + 255) / 256;

    if (csr) {
        k_init<<<512, 256, 0, stream>>>(denom, deg);
        k_gemm<<<N_NODES / GROWS, 256, 0, stream>>>(feat, W, attn_l, attn_r, h, el, er);
        k_denom_count<<<eb, 256, 0, stream>>>(src, dst, el, er, denom, deg);
        k_scanA<<<SCAN_NB, 256, 0, stream>>>(deg, bsum);
        k_scanB<<<1, 128, 0, stream>>>(bsum, boff);
        k_scanC<<<SCAN_NB, 256, 0, stream>>>(deg, boff, rowptr, cursor);
        k_scatter<<<eb, 256, 0, stream>>>(src, dst, el, er, denom, cursor,
                                          srcs, (float4*)aw);
        k_agg_csr<<<N_NODES / 4, 256, 0, stream>>>(rowptr, srcs, aw, h, out);
    } else {
        k_init_fb<<<2048, 256, 0, stream>>>(out, denom);
        k_gemm<<<N_NODES / GROWS, 256, 0, stream>>>(feat, W, attn_l, attn_r, h, el, er);
        k_denom_count<<<eb, 256, 0, stream>>>(src, dst, el, er, denom, (int*)nullptr);
        long long tot = (long long)N_EDGES * HD;
        int ab = (int)((tot + 255) / 256);
        k_agg_fb<<<ab, 256, 0, stream>>>(src, dst, el, er, denom, h, out);
    }
}

// Round 4
// 381.231 us; speedup vs baseline: 3.7692x; 1.7806x over previous
//
#include <hip/hip_runtime.h>

#define N_NODES 100000
#define N_EDGES 1600000
#define DIN 128
#define NH 4
#define ND 32
#define HD 128   // NH*ND
#define NEG_SLOPE 0.2f
#define SCAN_NB 98   // ceil(N_NODES / 1024)

__device__ __forceinline__ float lrelu(float x) {
    return x > 0.0f ? x : NEG_SLOPE * x;
}

// ---------------- init (CSR path): zero deg ------------------------------
__global__ void k_init(int* __restrict__ deg) {
    int i = blockIdx.x * blockDim.x + threadIdx.x;
    int stride = gridDim.x * blockDim.x;
    for (int j = i; j < N_NODES; j += stride) deg[j] = 0;
}

// ---------------- init (fallback path): zero out + denom -----------------
__global__ void k_init_fb(float* __restrict__ out, float* __restrict__ denom) {
    int i = blockIdx.x * blockDim.x + threadIdx.x;
    int stride = gridDim.x * blockDim.x;
    for (int j = i; j < N_NODES * HD; j += stride) out[j] = 0.0f;
    for (int j = i; j < N_NODES * NH; j += stride) denom[j] = 0.0f;
}

// ---------------- GEMM h = feat @ W, fused el/er -------------------------
// block 256 threads, tile 32 rows x 128 cols, thread = 4 rows x 4 cols.
#define GROWS 32
__global__ __launch_bounds__(256) void k_gemm(
    const float* __restrict__ feat, const float* __restrict__ W,
    const float* __restrict__ attn_l, const float* __restrict__ attn_r,
    float* __restrict__ h, float* __restrict__ el, float* __restrict__ er) {

    __shared__ float Ws[DIN * HD];      // 64 KB, [k][c]
    __shared__ float fs[GROWS * DIN];   // 16 KB, [r][k]

    const int tid = threadIdx.x;
    const int row0 = blockIdx.x * GROWS;

    {   // stage W: 4096 float4
        const float4* Wv = (const float4*)W;
        float4* Sv = (float4*)Ws;
#pragma unroll
        for (int it = 0; it < 16; ++it) Sv[tid + it * 256] = Wv[tid + it * 256];
    }
    {   // stage 32 feat rows: 1024 float4
        const float4* Fv = (const float4*)(feat + (size_t)row0 * DIN);
        float4* Sv = (float4*)fs;
#pragma unroll
        for (int it = 0; it < 4; ++it) Sv[tid + it * 256] = Fv[tid + it * 256];
    }
    __syncthreads();

    const int cg = tid & 31;   // cols 4*cg .. 4*cg+3
    const int rg = tid >> 5;   // rows 4*rg .. 4*rg+3

    float acc[4][4];
#pragma unroll
    for (int r = 0; r < 4; ++r)
#pragma unroll
        for (int c = 0; c < 4; ++c) acc[r][c] = 0.0f;

#pragma unroll 4
    for (int k = 0; k < DIN; ++k) {
        float4 w = *(const float4*)&Ws[k * HD + cg * 4];
#pragma unroll
        for (int r = 0; r < 4; ++r) {
            float f = fs[(rg * 4 + r) * DIN + k];
            acc[r][0] = fmaf(f, w.x, acc[r][0]);
            acc[r][1] = fmaf(f, w.y, acc[r][1]);
            acc[r][2] = fmaf(f, w.z, acc[r][2]);
            acc[r][3] = fmaf(f, w.w, acc[r][3]);
        }
    }

    const float4 alv = *(const float4*)(attn_l + cg * 4);
    const float4 arv = *(const float4*)(attn_r + cg * 4);
    const int head = cg >> 3;

#pragma unroll
    for (int r = 0; r < 4; ++r) {
        int row = row0 + rg * 4 + r;
        *(float4*)&h[(size_t)row * HD + cg * 4] =
            make_float4(acc[r][0], acc[r][1], acc[r][2], acc[r][3]);
        float vl = acc[r][0] * alv.x + acc[r][1] * alv.y +
                   acc[r][2] * alv.z + acc[r][3] * alv.w;
        float vr = acc[r][0] * arv.x + acc[r][1] * arv.y +
                   acc[r][2] * arv.z + acc[r][3] * arv.w;
        vl += __shfl_down(vl, 4, 64);
        vl += __shfl_down(vl, 2, 64);
        vl += __shfl_down(vl, 1, 64);
        vr += __shfl_down(vr, 4, 64);
        vr += __shfl_down(vr, 2, 64);
        vr += __shfl_down(vr, 1, 64);
        if ((cg & 7) == 0) {
            el[(size_t)row * NH + head] = vl;
            er[(size_t)row * NH + head] = vr;
        }
    }
}

// ---------------- degree count, keep per-edge rank -----------------------
// rank[e] = this edge's (arbitrary but unique) index among edges with the
// same dst -> scatter needs no atomics.
__global__ __launch_bounds__(256) void k_count(
    const int* __restrict__ dst, int* __restrict__ deg, int* __restrict__ rank) {
    int t = blockIdx.x * blockDim.x + threadIdx.x;
    int e = t * 4;
    if (e >= N_EDGES) return;
    int4 d = *(const int4*)(dst + e);
    int r0 = atomicAdd(deg + d.x, 1);
    int r1 = atomicAdd(deg + d.y, 1);
    int r2 = atomicAdd(deg + d.z, 1);
    int r3 = atomicAdd(deg + d.w, 1);
    *(int4*)(rank + e) = make_int4(r0, r1, r2, r3);
}

// ---------------- scan: deg -> rowptr (exclusive) ------------------------
__global__ __launch_bounds__(256) void k_scanA(const int* __restrict__ deg,
                                               int* __restrict__ bsum) {
    __shared__ int wsum[4];
    int b = blockIdx.x, tid = threadIdx.x;
    int base = b * 1024 + tid * 4;
    int s = 0;
#pragma unroll
    for (int j = 0; j < 4; ++j) {
        int i = base + j;
        if (i < N_NODES) s += deg[i];
    }
#pragma unroll
    for (int off = 32; off >= 1; off >>= 1) s += __shfl_down(s, off, 64);
    if ((tid & 63) == 0) wsum[tid >> 6] = s;
    __syncthreads();
    if (tid == 0) bsum[b] = wsum[0] + wsum[1] + wsum[2] + wsum[3];
}

__global__ __launch_bounds__(128) void k_scanB(const int* __restrict__ bsum,
                                               int* __restrict__ boff) {
    __shared__ int tmp[SCAN_NB];
    int tid = threadIdx.x;
    if (tid < SCAN_NB) tmp[tid] = bsum[tid];
    __syncthreads();
    if (tid == 0) {
        int acc = 0;
        for (int i = 0; i < SCAN_NB; ++i) { int v = tmp[i]; tmp[i] = acc; acc += v; }
    }
    __syncthreads();
    if (tid < SCAN_NB) boff[tid] = tmp[tid];
}

__global__ __launch_bounds__(256) void k_scanC(const int* __restrict__ deg,
                                               const int* __restrict__ boff,
                                               int* __restrict__ rowptr) {
    __shared__ int wtot[4];
    int b = blockIdx.x, tid = threadIdx.x;
    int base = b * 1024 + tid * 4;
    int d[4];
#pragma unroll
    for (int j = 0; j < 4; ++j) {
        int i = base + j;
        d[j] = (i < N_NODES) ? deg[i] : 0;
    }
    int tsum = d[0] + d[1] + d[2] + d[3];
    int lane = tid & 63;
    int v = tsum;
#pragma unroll
    for (int off = 1; off < 64; off <<= 1) {
        int t = __shfl_up(v, off, 64);
        if (lane >= off) v += t;
    }
    if (lane == 63) wtot[tid >> 6] = v;
    int texcl = v - tsum;
    __syncthreads();
    int woff = 0;
    for (int w = 0; w < (tid >> 6); ++w) woff += wtot[w];
    int pfx = boff[b] + woff + texcl;
#pragma unroll
    for (int j = 0; j < 4; ++j) {
        int i = base + j;
        if (i < N_NODES) rowptr[i] = pfx;
        else if (i == N_NODES) rowptr[i] = pfx;
        pfx += d[j];
    }
}

// ---------------- scatter: sorted-by-dst (src, unnormalized exp) ---------
// slot = rowptr[d] + rank[e]  -> atomic-free.
__global__ __launch_bounds__(256) void k_scatter(
    const int* __restrict__ src, const int* __restrict__ dst,
    const int* __restrict__ rank, const int* __restrict__ rowptr,
    const float* __restrict__ el, const float* __restrict__ er,
    int* __restrict__ srcs, float4* __restrict__ aw) {
    int e = blockIdx.x * blockDim.x + threadIdx.x;
    if (e >= N_EDGES) return;
    int s = src[e], d = dst[e];
    float4 l = *(const float4*)(el + (size_t)s * NH);
    float4 r = *(const float4*)(er + (size_t)d * NH);
    float4 w = make_float4(__expf(lrelu(l.x + r.x)),
                           __expf(lrelu(l.y + r.y)),
                           __expf(lrelu(l.z + r.z)),
                           __expf(lrelu(l.w + r.w)));
    int slot = rowptr[d] + rank[e];
    srcs[slot] = s;
    aw[slot] = w;
}

// ---------------- CSR gather-aggregate -----------------------------------
// One 64-lane wave per dst node; lane covers 2 channels (float2).
// Pass 1: per-node denominator (sequential sum, no atomics).
// Pass 2: normalize + accumulate; out written exactly once.
__global__ __launch_bounds__(256) void k_agg_csr(
    const int* __restrict__ rowptr, const int* __restrict__ srcs,
    const float* __restrict__ aw, const float* __restrict__ h,
    float* __restrict__ out) {
    int node = blockIdx.x * 4 + (threadIdx.x >> 6);
    int lane = threadIdx.x & 63;
    int c2 = lane * 2;
    int hh = lane >> 4;
    int beg = rowptr[node], end = rowptr[node + 1];

    float dsum = 0.0f;
    for (int i = beg; i < end; ++i) dsum += aw[(size_t)i * 4 + hh];
    float inv = (end > beg) ? 1.0f / dsum : 0.0f;

    float a0 = 0.0f, a1 = 0.0f;
    int i = beg;
    for (; i + 2 <= end; i += 2) {
        int s0 = srcs[i], s1 = srcs[i + 1];
        float w0 = aw[(size_t)i * 4 + hh] * inv;
        float w1 = aw[(size_t)(i + 1) * 4 + hh] * inv;
        float2 h0 = *(const float2*)(h + (size_t)s0 * HD + c2);
        float2 h1 = *(const float2*)(h + (size_t)s1 * HD + c2);
        a0 = fmaf(h0.x, w0, a0); a1 = fmaf(h0.y, w0, a1);
        a0 = fmaf(h1.x, w1, a0); a1 = fmaf(h1.y, w1, a1);
    }
    if (i < end) {
        int s0 = srcs[i];
        float w0 = aw[(size_t)i * 4 + hh] * inv;
        float2 h0 = *(const float2*)(h + (size_t)s0 * HD + c2);
        a0 = fmaf(h0.x, w0, a0); a1 = fmaf(h0.y, w0, a1);
    }
    *(float2*)(out + (size_t)node * HD + c2) = make_float2(a0, a1);
}

// ---------------- fallback path (atomics) --------------------------------
__global__ __launch_bounds__(256) void k_denom_fb(
    const int* __restrict__ src, const int* __restrict__ dst,
    const float* __restrict__ el, const float* __restrict__ er,
    float* __restrict__ denom) {
    int e = blockIdx.x * blockDim.x + threadIdx.x;
    if (e >= N_EDGES) return;
    int s = src[e], d = dst[e];
    float4 l = *(const float4*)(el + (size_t)s * NH);
    float4 r = *(const float4*)(er + (size_t)d * NH);
    float* dn = denom + (size_t)d * NH;
    atomicAdd(dn + 0, __expf(lrelu(l.x + r.x)));
    atomicAdd(dn + 1, __expf(lrelu(l.y + r.y)));
    atomicAdd(dn + 2, __expf(lrelu(l.z + r.z)));
    atomicAdd(dn + 3, __expf(lrelu(l.w + r.w)));
}

__global__ __launch_bounds__(256) void k_agg_fb(
    const int* __restrict__ src, const int* __restrict__ dst,
    const float* __restrict__ el, const float* __restrict__ er,
    const float* __restrict__ denom, const float* __restrict__ h,
    float* __restrict__ out) {
    long long t = (long long)blockIdx.x * blockDim.x + threadIdx.x;
    if (t >= (long long)N_EDGES * HD) return;
    int e = (int)(t >> 7);
    int c = (int)(t & 127);
    int hh = c >> 5;
    int s = src[e], d = dst[e];
    float x = lrelu(el[(size_t)s * NH + hh] + er[(size_t)d * NH + hh]);
    float a = __expf(x) / denom[(size_t)d * NH + hh];
    atomicAdd(out + (size_t)d * HD + c, h[(size_t)s * HD + c] * a);
}

extern "C" void kernel_launch(void* const* d_in, const int* in_sizes, int n_in,
                              void* d_out, int out_size, void* d_ws, size_t ws_size,
                              hipStream_t stream) {
    const float* feat   = (const float*)d_in[0];
    const int*   src    = (const int*)d_in[1];
    const int*   dst    = (const int*)d_in[2];
    const float* W      = (const float*)d_in[3];
    const float* attn_l = (const float*)d_in[4];
    const float* attn_r = (const float*)d_in[5];
    float* out = (float*)d_out;

    char* base = (char*)d_ws;
    size_t off = 0;
    auto take = [&](size_t bytes) -> char* {
        char* r = base + off;
        off = (off + bytes + 255) & ~(size_t)255;
        return r;
    };
    float* h      = (float*)take((size_t)N_NODES * HD * 4);
    float* el     = (float*)take((size_t)N_NODES * NH * 4);
    float* er     = (float*)take((size_t)N_NODES * NH * 4);
    int*   deg    = (int*)take((size_t)N_NODES * 4);
    int*   rowptr = (int*)take((size_t)(N_NODES + 1) * 4);
    int*   rank   = (int*)take((size_t)N_EDGES * 4);
    int*   bsum   = (int*)take(SCAN_NB * 4);
    int*   boff   = (int*)take(SCAN_NB * 4);
    int*   srcs   = (int*)take((size_t)N_EDGES * 4);
    float* aw     = (float*)take((size_t)N_EDGES * NH * 4);
    float* denom  = (float*)take((size_t)N_NODES * NH * 4); // fallback only
    bool csr = (off <= ws_size);

    int eb = (N_EDGES + 255) / 256;

    if (csr) {
        k_init<<<128, 256, 0, stream>>>(deg);
        k_gemm<<<N_NODES / GROWS, 256, 0, stream>>>(feat, W, attn_l, attn_r, h, el, er);
        k_count<<<(N_EDGES / 4 + 255) / 256, 256, 0, stream>>>(dst, deg, rank);
        k_scanA<<<SCAN_NB, 256, 0, stream>>>(deg, bsum);
        k_scanB<<<1, 128, 0, stream>>>(bsum, boff);
        k_scanC<<<SCAN_NB, 256, 0, stream>>>(deg, boff, rowptr);
        k_scatter<<<eb, 256, 0, stream>>>(src, dst, rank, rowptr, el, er,
                                          srcs, (float4*)aw);
        k_agg_csr<<<N_NODES / 4, 256, 0, stream>>>(rowptr, srcs, aw, h, out);
    } else {
        k_init_fb<<<2048, 256, 0, stream>>>(out, denom);
        k_gemm<<<N_NODES / GROWS, 256, 0, stream>>>(feat, W, attn_l, attn_r, h, el, er);
        k_denom_fb<<<eb, 256, 0, stream>>>(src, dst, el, er, denom);
        long long tot = (long long)N_EDGES * HD;
        int ab = (int)((tot + 255) / 256);
        k_agg_fb<<<ab, 256, 0, stream>>>(src, dst, el, er, denom, h, out);
    }
}

// Round 5
// 273.497 us; speedup vs baseline: 5.2540x; 1.3939x over previous
//
#include <hip/hip_runtime.h>
#include <hip/hip_fp16.h>

#define N_NODES 100000
#define N_EDGES 1600000
#define DIN 128
#define NH 4
#define ND 32
#define HD 128   // NH*ND
#define NEG_SLOPE 0.2f
#define SCAN_NB 98   // ceil(N_NODES / 1024)

__device__ __forceinline__ float lrelu(float x) {
    return x > 0.0f ? x : NEG_SLOPE * x;
}

union Pack8 { uint2 u; __half2 h2[2]; };

// ---------------- init (CSR path): zero deg ------------------------------
__global__ void k_init(int* __restrict__ deg) {
    int i = blockIdx.x * blockDim.x + threadIdx.x;
    int stride = gridDim.x * blockDim.x;
    for (int j = i; j < N_NODES; j += stride) deg[j] = 0;
}

// ---------------- init (fallback path): zero out + denom -----------------
__global__ void k_init_fb(float* __restrict__ out, float* __restrict__ denom) {
    int i = blockIdx.x * blockDim.x + threadIdx.x;
    int stride = gridDim.x * blockDim.x;
    for (int j = i; j < N_NODES * HD; j += stride) out[j] = 0.0f;
    for (int j = i; j < N_NODES * NH; j += stride) denom[j] = 0.0f;
}

// ---------------- GEMM h = feat @ W (fp16 out), fused el/er --------------
// block 256 threads, tile 32 rows x 128 cols, thread = 4 rows x 4 cols.
// k-loop: 4 k per iter -> 8x ds_read_b128 per 64 FMAs.
#define GROWS 32
__global__ __launch_bounds__(256) void k_gemm(
    const float* __restrict__ feat, const float* __restrict__ W,
    const float* __restrict__ attn_l, const float* __restrict__ attn_r,
    __half* __restrict__ hhalf, float* __restrict__ el, float* __restrict__ er) {

    __shared__ float Ws[DIN * HD];      // 64 KB, [k][c]
    __shared__ float fs[GROWS * DIN];   // 16 KB, [r][k]

    const int tid = threadIdx.x;
    const int row0 = blockIdx.x * GROWS;

    {   // stage W: 4096 float4
        const float4* Wv = (const float4*)W;
        float4* Sv = (float4*)Ws;
#pragma unroll
        for (int it = 0; it < 16; ++it) Sv[tid + it * 256] = Wv[tid + it * 256];
    }
    {   // stage 32 feat rows: 1024 float4
        const float4* Fv = (const float4*)(feat + (size_t)row0 * DIN);
        float4* Sv = (float4*)fs;
#pragma unroll
        for (int it = 0; it < 4; ++it) Sv[tid + it * 256] = Fv[tid + it * 256];
    }
    __syncthreads();

    const int cg = tid & 31;   // cols 4*cg .. 4*cg+3
    const int rg = tid >> 5;   // rows 4*rg .. 4*rg+3

    float acc[4][4];
#pragma unroll
    for (int r = 0; r < 4; ++r)
#pragma unroll
        for (int c = 0; c < 4; ++c) acc[r][c] = 0.0f;

    for (int k = 0; k < DIN; k += 4) {
        float4 f0 = *(const float4*)&fs[(rg * 4 + 0) * DIN + k];
        float4 f1 = *(const float4*)&fs[(rg * 4 + 1) * DIN + k];
        float4 f2 = *(const float4*)&fs[(rg * 4 + 2) * DIN + k];
        float4 f3 = *(const float4*)&fs[(rg * 4 + 3) * DIN + k];
        const float* fp0 = (const float*)&f0;
        const float* fp1 = (const float*)&f1;
        const float* fp2 = (const float*)&f2;
        const float* fp3 = (const float*)&f3;
#pragma unroll
        for (int kk = 0; kk < 4; ++kk) {
            float4 w = *(const float4*)&Ws[(k + kk) * HD + cg * 4];
            float b0 = fp0[kk], b1 = fp1[kk], b2 = fp2[kk], b3 = fp3[kk];
            acc[0][0] = fmaf(b0, w.x, acc[0][0]);
            acc[0][1] = fmaf(b0, w.y, acc[0][1]);
            acc[0][2] = fmaf(b0, w.z, acc[0][2]);
            acc[0][3] = fmaf(b0, w.w, acc[0][3]);
            acc[1][0] = fmaf(b1, w.x, acc[1][0]);
            acc[1][1] = fmaf(b1, w.y, acc[1][1]);
            acc[1][2] = fmaf(b1, w.z, acc[1][2]);
            acc[1][3] = fmaf(b1, w.w, acc[1][3]);
            acc[2][0] = fmaf(b2, w.x, acc[2][0]);
            acc[2][1] = fmaf(b2, w.y, acc[2][1]);
            acc[2][2] = fmaf(b2, w.z, acc[2][2]);
            acc[2][3] = fmaf(b2, w.w, acc[2][3]);
            acc[3][0] = fmaf(b3, w.x, acc[3][0]);
            acc[3][1] = fmaf(b3, w.y, acc[3][1]);
            acc[3][2] = fmaf(b3, w.z, acc[3][2]);
            acc[3][3] = fmaf(b3, w.w, acc[3][3]);
        }
    }

    const float4 alv = *(const float4*)(attn_l + cg * 4);
    const float4 arv = *(const float4*)(attn_r + cg * 4);
    const int head = cg >> 3;

#pragma unroll
    for (int r = 0; r < 4; ++r) {
        int row = row0 + rg * 4 + r;
        Pack8 pk;
        pk.h2[0] = __floats2half2_rn(acc[r][0], acc[r][1]);
        pk.h2[1] = __floats2half2_rn(acc[r][2], acc[r][3]);
        *(uint2*)(hhalf + (size_t)row * HD + cg * 4) = pk.u;
        float vl = acc[r][0] * alv.x + acc[r][1] * alv.y +
                   acc[r][2] * alv.z + acc[r][3] * alv.w;
        float vr = acc[r][0] * arv.x + acc[r][1] * arv.y +
                   acc[r][2] * arv.z + acc[r][3] * arv.w;
        vl += __shfl_down(vl, 4, 64);
        vl += __shfl_down(vl, 2, 64);
        vl += __shfl_down(vl, 1, 64);
        vr += __shfl_down(vr, 4, 64);
        vr += __shfl_down(vr, 2, 64);
        vr += __shfl_down(vr, 1, 64);
        if ((cg & 7) == 0) {
            el[(size_t)row * NH + head] = vl;
            er[(size_t)row * NH + head] = vr;
        }
    }
}

// ---------------- degree count, keep per-edge rank -----------------------
// 1 edge/thread: max parallel atomic issue.
__global__ __launch_bounds__(256) void k_count(
    const int* __restrict__ dst, int* __restrict__ deg, int* __restrict__ rank) {
    int e = blockIdx.x * blockDim.x + threadIdx.x;
    if (e >= N_EDGES) return;
    rank[e] = atomicAdd(deg + dst[e], 1);
}

// ---------------- scan: deg -> rowptr (exclusive) ------------------------
__global__ __launch_bounds__(256) void k_scanA(const int* __restrict__ deg,
                                               int* __restrict__ bsum) {
    __shared__ int wsum[4];
    int b = blockIdx.x, tid = threadIdx.x;
    int base = b * 1024 + tid * 4;
    int s = 0;
#pragma unroll
    for (int j = 0; j < 4; ++j) {
        int i = base + j;
        if (i < N_NODES) s += deg[i];
    }
#pragma unroll
    for (int off = 32; off >= 1; off >>= 1) s += __shfl_down(s, off, 64);
    if ((tid & 63) == 0) wsum[tid >> 6] = s;
    __syncthreads();
    if (tid == 0) bsum[b] = wsum[0] + wsum[1] + wsum[2] + wsum[3];
}

__global__ __launch_bounds__(128) void k_scanB(const int* __restrict__ bsum,
                                               int* __restrict__ boff) {
    __shared__ int tmp[SCAN_NB];
    int tid = threadIdx.x;
    if (tid < SCAN_NB) tmp[tid] = bsum[tid];
    __syncthreads();
    if (tid == 0) {
        int acc = 0;
        for (int i = 0; i < SCAN_NB; ++i) { int v = tmp[i]; tmp[i] = acc; acc += v; }
    }
    __syncthreads();
    if (tid < SCAN_NB) boff[tid] = tmp[tid];
}

__global__ __launch_bounds__(256) void k_scanC(const int* __restrict__ deg,
                                               const int* __restrict__ boff,
                                               int* __restrict__ rowptr) {
    __shared__ int wtot[4];
    int b = blockIdx.x, tid = threadIdx.x;
    int base = b * 1024 + tid * 4;
    int d[4];
#pragma unroll
    for (int j = 0; j < 4; ++j) {
        int i = base + j;
        d[j] = (i < N_NODES) ? deg[i] : 0;
    }
    int tsum = d[0] + d[1] + d[2] + d[3];
    int lane = tid & 63;
    int v = tsum;
#pragma unroll
    for (int off = 1; off < 64; off <<= 1) {
        int t = __shfl_up(v, off, 64);
        if (lane >= off) v += t;
    }
    if (lane == 63) wtot[tid >> 6] = v;
    int texcl = v - tsum;
    __syncthreads();
    int woff = 0;
    for (int w = 0; w < (tid >> 6); ++w) woff += wtot[w];
    int pfx = boff[b] + woff + texcl;
#pragma unroll
    for (int j = 0; j < 4; ++j) {
        int i = base + j;
        if (i < N_NODES) rowptr[i] = pfx;
        else if (i == N_NODES) rowptr[i] = pfx;
        pfx += d[j];
    }
}

// ---------------- scatter: sorted-by-dst (src, unnormalized exp fp16) ----
// slot = rowptr[d] + rank[e]  -> atomic-free.
__global__ __launch_bounds__(256) void k_scatter(
    const int* __restrict__ src, const int* __restrict__ dst,
    const int* __restrict__ rank, const int* __restrict__ rowptr,
    const float* __restrict__ el, const float* __restrict__ er,
    int* __restrict__ srcs, __half* __restrict__ awh) {
    int e = blockIdx.x * blockDim.x + threadIdx.x;
    if (e >= N_EDGES) return;
    int s = src[e], d = dst[e];
    float4 l = *(const float4*)(el + (size_t)s * NH);
    float4 r = *(const float4*)(er + (size_t)d * NH);
    Pack8 pk;
    pk.h2[0] = __floats2half2_rn(__expf(lrelu(l.x + r.x)),
                                 __expf(lrelu(l.y + r.y)));
    pk.h2[1] = __floats2half2_rn(__expf(lrelu(l.z + r.z)),
                                 __expf(lrelu(l.w + r.w)));
    int slot = rowptr[d] + rank[e];
    srcs[slot] = s;
    *(uint2*)(awh + (size_t)slot * 4) = pk.u;
}

// ---------------- CSR gather-aggregate (single pass) ----------------------
// One 64-lane wave per dst node. lane = (grp=edge-parity)<<5 | cl.
// cl covers channels cl*4..cl*4+3 (half4 = 8 B load). Accumulate
// UNNORMALIZED sums + denominator in one pass, scale by 1/denom at end
// (softmax is linear in the scale). Cross-parity add via shfl_xor(32).
__global__ __launch_bounds__(256) void k_agg_csr(
    const int* __restrict__ rowptr, const int* __restrict__ srcs,
    const __half* __restrict__ awh, const __half* __restrict__ hhalf,
    float* __restrict__ out) {
    int node = blockIdx.x * 4 + (threadIdx.x >> 6);
    int lane = threadIdx.x & 63;
    int grp = lane >> 5;
    int cl = lane & 31;
    int head = cl >> 3;
    int beg = rowptr[node], end = rowptr[node + 1];

    float dsum = 0.0f;
    float a0 = 0.0f, a1 = 0.0f, a2 = 0.0f, a3 = 0.0f;

    int i = beg + grp;
    for (; i + 2 < end; i += 4) {
        int s0 = srcs[i];
        int s1 = srcs[i + 2];
        float w0 = __half2float(awh[(size_t)i * 4 + head]);
        float w1 = __half2float(awh[(size_t)(i + 2) * 4 + head]);
        Pack8 p0, p1;
        p0.u = *(const uint2*)(hhalf + (size_t)s0 * HD + cl * 4);
        p1.u = *(const uint2*)(hhalf + (size_t)s1 * HD + cl * 4);
        dsum += w0 + w1;
        float2 x0 = __half22float2(p0.h2[0]), y0 = __half22float2(p0.h2[1]);
        float2 x1 = __half22float2(p1.h2[0]), y1 = __half22float2(p1.h2[1]);
        a0 = fmaf(x0.x, w0, a0); a1 = fmaf(x0.y, w0, a1);
        a2 = fmaf(y0.x, w0, a2); a3 = fmaf(y0.y, w0, a3);
        a0 = fmaf(x1.x, w1, a0); a1 = fmaf(x1.y, w1, a1);
        a2 = fmaf(y1.x, w1, a2); a3 = fmaf(y1.y, w1, a3);
    }
    if (i < end) {
        int s0 = srcs[i];
        float w0 = __half2float(awh[(size_t)i * 4 + head]);
        Pack8 p0;
        p0.u = *(const uint2*)(hhalf + (size_t)s0 * HD + cl * 4);
        dsum += w0;
        float2 x0 = __half22float2(p0.h2[0]), y0 = __half22float2(p0.h2[1]);
        a0 = fmaf(x0.x, w0, a0); a1 = fmaf(x0.y, w0, a1);
        a2 = fmaf(y0.x, w0, a2); a3 = fmaf(y0.y, w0, a3);
    }

    dsum += __shfl_xor(dsum, 32, 64);
    a0 += __shfl_xor(a0, 32, 64);
    a1 += __shfl_xor(a1, 32, 64);
    a2 += __shfl_xor(a2, 32, 64);
    a3 += __shfl_xor(a3, 32, 64);

    if (grp == 0) {
        float inv = (end > beg) ? 1.0f / dsum : 0.0f;
        *(float4*)(out + (size_t)node * HD + cl * 4) =
            make_float4(a0 * inv, a1 * inv, a2 * inv, a3 * inv);
    }
}

// ---------------- fallback path (atomics) --------------------------------
__global__ __launch_bounds__(256) void k_denom_fb(
    const int* __restrict__ src, const int* __restrict__ dst,
    const float* __restrict__ el, const float* __restrict__ er,
    float* __restrict__ denom) {
    int e = blockIdx.x * blockDim.x + threadIdx.x;
    if (e >= N_EDGES) return;
    int s = src[e], d = dst[e];
    float4 l = *(const float4*)(el + (size_t)s * NH);
    float4 r = *(const float4*)(er + (size_t)d * NH);
    float* dn = denom + (size_t)d * NH;
    atomicAdd(dn + 0, __expf(lrelu(l.x + r.x)));
    atomicAdd(dn + 1, __expf(lrelu(l.y + r.y)));
    atomicAdd(dn + 2, __expf(lrelu(l.z + r.z)));
    atomicAdd(dn + 3, __expf(lrelu(l.w + r.w)));
}

__global__ __launch_bounds__(256) void k_agg_fb(
    const int* __restrict__ src, const int* __restrict__ dst,
    const float* __restrict__ el, const float* __restrict__ er,
    const float* __restrict__ denom, const __half* __restrict__ hhalf,
    float* __restrict__ out) {
    long long t = (long long)blockIdx.x * blockDim.x + threadIdx.x;
    if (t >= (long long)N_EDGES * HD) return;
    int e = (int)(t >> 7);
    int c = (int)(t & 127);
    int hh = c >> 5;
    int s = src[e], d = dst[e];
    float x = lrelu(el[(size_t)s * NH + hh] + er[(size_t)d * NH + hh]);
    float a = __expf(x) / denom[(size_t)d * NH + hh];
    atomicAdd(out + (size_t)d * HD + c,
              __half2float(hhalf[(size_t)s * HD + c]) * a);
}

extern "C" void kernel_launch(void* const* d_in, const int* in_sizes, int n_in,
                              void* d_out, int out_size, void* d_ws, size_t ws_size,
                              hipStream_t stream) {
    const float* feat   = (const float*)d_in[0];
    const int*   src    = (const int*)d_in[1];
    const int*   dst    = (const int*)d_in[2];
    const float* W      = (const float*)d_in[3];
    const float* attn_l = (const float*)d_in[4];
    const float* attn_r = (const float*)d_in[5];
    float* out = (float*)d_out;

    char* base = (char*)d_ws;
    size_t off = 0;
    auto take = [&](size_t bytes) -> char* {
        char* r = base + off;
        off = (off + bytes + 255) & ~(size_t)255;
        return r;
    };
    __half* hhalf = (__half*)take((size_t)N_NODES * HD * 2);
    float* el     = (float*)take((size_t)N_NODES * NH * 4);
    float* er     = (float*)take((size_t)N_NODES * NH * 4);
    int*   deg    = (int*)take((size_t)N_NODES * 4);
    int*   rowptr = (int*)take((size_t)(N_NODES + 1) * 4);
    int*   rank   = (int*)take((size_t)N_EDGES * 4);
    int*   bsum   = (int*)take(SCAN_NB * 4);
    int*   boff   = (int*)take(SCAN_NB * 4);
    int*   srcs   = (int*)take((size_t)N_EDGES * 4);
    __half* awh   = (__half*)take((size_t)N_EDGES * NH * 2);
    float* denom  = (float*)take((size_t)N_NODES * NH * 4); // fallback only
    bool csr = (off <= ws_size);

    int eb = (N_EDGES + 255) / 256;

    if (csr) {
        k_init<<<128, 256, 0, stream>>>(deg);
        k_gemm<<<N_NODES / GROWS, 256, 0, stream>>>(feat, W, attn_l, attn_r,
                                                    hhalf, el, er);
        k_count<<<eb, 256, 0, stream>>>(dst, deg, rank);
        k_scanA<<<SCAN_NB, 256, 0, stream>>>(deg, bsum);
        k_scanB<<<1, 128, 0, stream>>>(bsum, boff);
        k_scanC<<<SCAN_NB, 256, 0, stream>>>(deg, boff, rowptr);
        k_scatter<<<eb, 256, 0, stream>>>(src, dst, rank, rowptr, el, er,
                                          srcs, awh);
        k_agg_csr<<<N_NODES / 4, 256, 0, stream>>>(rowptr, srcs, awh, hhalf, out);
    } else {
        k_init_fb<<<2048, 256, 0, stream>>>(out, denom);
        k_gemm<<<N_NODES / GROWS, 256, 0, stream>>>(feat, W, attn_l, attn_r,
                                                    hhalf, el, er);
        k_denom_fb<<<eb, 256, 0, stream>>>(src, dst, el, er, denom);
        long long tot = (long long)N_EDGES * HD;
        int ab = (int)((tot + 255) / 256);
        k_agg_fb<<<ab, 256, 0, stream>>>(src, dst, el, er, denom, hhalf, out);
    }
}

// Round 6
// 236.304 us; speedup vs baseline: 6.0810x; 1.1574x over previous
//
#include <hip/hip_runtime.h>
#include <hip/hip_fp16.h>

#define N_NODES 100000
#define N_EDGES 1600000
#define DIN 128
#define NH 4
#define ND 32
#define HD 128   // NH*ND
#define NEG_SLOPE 0.2f
#define SCAN_NB 98   // ceil(N_NODES / 1024)

__device__ __forceinline__ float lrelu(float x) {
    return x > 0.0f ? x : NEG_SLOPE * x;
}

union Pack8 { uint2 u; __half2 h2[2]; };

// ---------------- init (CSR path): zero deg ------------------------------
__global__ void k_init(int* __restrict__ deg) {
    int i = blockIdx.x * blockDim.x + threadIdx.x;
    int stride = gridDim.x * blockDim.x;
    for (int j = i; j < N_NODES; j += stride) deg[j] = 0;
}

// ---------------- init (fallback path): zero out + denom -----------------
__global__ void k_init_fb(float* __restrict__ out, float* __restrict__ denom) {
    int i = blockIdx.x * blockDim.x + threadIdx.x;
    int stride = gridDim.x * blockDim.x;
    for (int j = i; j < N_NODES * HD; j += stride) out[j] = 0.0f;
    for (int j = i; j < N_NODES * NH; j += stride) denom[j] = 0.0f;
}

// ---------------- GEMM h = feat @ W (fp16 out), fused el/er --------------
// block 256 threads, tile 32 rows x 128 cols, thread = 4 rows x 4 cols.
#define GROWS 32
__global__ __launch_bounds__(256) void k_gemm(
    const float* __restrict__ feat, const float* __restrict__ W,
    const float* __restrict__ attn_l, const float* __restrict__ attn_r,
    __half* __restrict__ hhalf, float* __restrict__ el, float* __restrict__ er) {

    __shared__ float Ws[DIN * HD];      // 64 KB, [k][c]
    __shared__ float fs[GROWS * DIN];   // 16 KB, [r][k]

    const int tid = threadIdx.x;
    const int row0 = blockIdx.x * GROWS;

    {   // stage W: 4096 float4
        const float4* Wv = (const float4*)W;
        float4* Sv = (float4*)Ws;
#pragma unroll
        for (int it = 0; it < 16; ++it) Sv[tid + it * 256] = Wv[tid + it * 256];
    }
    {   // stage 32 feat rows: 1024 float4
        const float4* Fv = (const float4*)(feat + (size_t)row0 * DIN);
        float4* Sv = (float4*)fs;
#pragma unroll
        for (int it = 0; it < 4; ++it) Sv[tid + it * 256] = Fv[tid + it * 256];
    }
    __syncthreads();

    const int cg = tid & 31;   // cols 4*cg .. 4*cg+3
    const int rg = tid >> 5;   // rows 4*rg .. 4*rg+3

    float acc[4][4];
#pragma unroll
    for (int r = 0; r < 4; ++r)
#pragma unroll
        for (int c = 0; c < 4; ++c) acc[r][c] = 0.0f;

    for (int k = 0; k < DIN; k += 4) {
        float4 f0 = *(const float4*)&fs[(rg * 4 + 0) * DIN + k];
        float4 f1 = *(const float4*)&fs[(rg * 4 + 1) * DIN + k];
        float4 f2 = *(const float4*)&fs[(rg * 4 + 2) * DIN + k];
        float4 f3 = *(const float4*)&fs[(rg * 4 + 3) * DIN + k];
        const float* fp0 = (const float*)&f0;
        const float* fp1 = (const float*)&f1;
        const float* fp2 = (const float*)&f2;
        const float* fp3 = (const float*)&f3;
#pragma unroll
        for (int kk = 0; kk < 4; ++kk) {
            float4 w = *(const float4*)&Ws[(k + kk) * HD + cg * 4];
            float b0 = fp0[kk], b1 = fp1[kk], b2 = fp2[kk], b3 = fp3[kk];
            acc[0][0] = fmaf(b0, w.x, acc[0][0]);
            acc[0][1] = fmaf(b0, w.y, acc[0][1]);
            acc[0][2] = fmaf(b0, w.z, acc[0][2]);
            acc[0][3] = fmaf(b0, w.w, acc[0][3]);
            acc[1][0] = fmaf(b1, w.x, acc[1][0]);
            acc[1][1] = fmaf(b1, w.y, acc[1][1]);
            acc[1][2] = fmaf(b1, w.z, acc[1][2]);
            acc[1][3] = fmaf(b1, w.w, acc[1][3]);
            acc[2][0] = fmaf(b2, w.x, acc[2][0]);
            acc[2][1] = fmaf(b2, w.y, acc[2][1]);
            acc[2][2] = fmaf(b2, w.z, acc[2][2]);
            acc[2][3] = fmaf(b2, w.w, acc[2][3]);
            acc[3][0] = fmaf(b3, w.x, acc[3][0]);
            acc[3][1] = fmaf(b3, w.y, acc[3][1]);
            acc[3][2] = fmaf(b3, w.z, acc[3][2]);
            acc[3][3] = fmaf(b3, w.w, acc[3][3]);
        }
    }

    const float4 alv = *(const float4*)(attn_l + cg * 4);
    const float4 arv = *(const float4*)(attn_r + cg * 4);
    const int head = cg >> 3;

#pragma unroll
    for (int r = 0; r < 4; ++r) {
        int row = row0 + rg * 4 + r;
        Pack8 pk;
        pk.h2[0] = __floats2half2_rn(acc[r][0], acc[r][1]);
        pk.h2[1] = __floats2half2_rn(acc[r][2], acc[r][3]);
        *(uint2*)(hhalf + (size_t)row * HD + cg * 4) = pk.u;
        float vl = acc[r][0] * alv.x + acc[r][1] * alv.y +
                   acc[r][2] * alv.z + acc[r][3] * alv.w;
        float vr = acc[r][0] * arv.x + acc[r][1] * arv.y +
                   acc[r][2] * arv.z + acc[r][3] * arv.w;
        vl += __shfl_down(vl, 4, 64);
        vl += __shfl_down(vl, 2, 64);
        vl += __shfl_down(vl, 1, 64);
        vr += __shfl_down(vr, 4, 64);
        vr += __shfl_down(vr, 2, 64);
        vr += __shfl_down(vr, 1, 64);
        if ((cg & 7) == 0) {
            el[(size_t)row * NH + head] = vl;
            er[(size_t)row * NH + head] = vr;
        }
    }
}

// ---------------- degree count, keep per-edge rank -----------------------
__global__ __launch_bounds__(256) void k_count(
    const int* __restrict__ dst, int* __restrict__ deg, int* __restrict__ rank) {
    int e = blockIdx.x * blockDim.x + threadIdx.x;
    if (e >= N_EDGES) return;
    rank[e] = atomicAdd(deg + dst[e], 1);
}

// ---------------- scan: deg -> rowptr (exclusive) ------------------------
__global__ __launch_bounds__(256) void k_scanA(const int* __restrict__ deg,
                                               int* __restrict__ bsum) {
    __shared__ int wsum[4];
    int b = blockIdx.x, tid = threadIdx.x;
    int base = b * 1024 + tid * 4;
    int s = 0;
#pragma unroll
    for (int j = 0; j < 4; ++j) {
        int i = base + j;
        if (i < N_NODES) s += deg[i];
    }
#pragma unroll
    for (int off = 32; off >= 1; off >>= 1) s += __shfl_down(s, off, 64);
    if ((tid & 63) == 0) wsum[tid >> 6] = s;
    __syncthreads();
    if (tid == 0) bsum[b] = wsum[0] + wsum[1] + wsum[2] + wsum[3];
}

__global__ __launch_bounds__(128) void k_scanB(const int* __restrict__ bsum,
                                               int* __restrict__ boff) {
    __shared__ int tmp[SCAN_NB];
    int tid = threadIdx.x;
    if (tid < SCAN_NB) tmp[tid] = bsum[tid];
    __syncthreads();
    if (tid == 0) {
        int acc = 0;
        for (int i = 0; i < SCAN_NB; ++i) { int v = tmp[i]; tmp[i] = acc; acc += v; }
    }
    __syncthreads();
    if (tid < SCAN_NB) boff[tid] = tmp[tid];
}

__global__ __launch_bounds__(256) void k_scanC(const int* __restrict__ deg,
                                               const int* __restrict__ boff,
                                               int* __restrict__ rowptr) {
    __shared__ int wtot[4];
    int b = blockIdx.x, tid = threadIdx.x;
    int base = b * 1024 + tid * 4;
    int d[4];
#pragma unroll
    for (int j = 0; j < 4; ++j) {
        int i = base + j;
        d[j] = (i < N_NODES) ? deg[i] : 0;
    }
    int tsum = d[0] + d[1] + d[2] + d[3];
    int lane = tid & 63;
    int v = tsum;
#pragma unroll
    for (int off = 1; off < 64; off <<= 1) {
        int t = __shfl_up(v, off, 64);
        if (lane >= off) v += t;
    }
    if (lane == 63) wtot[tid >> 6] = v;
    int texcl = v - tsum;
    __syncthreads();
    int woff = 0;
    for (int w = 0; w < (tid >> 6); ++w) woff += wtot[w];
    int pfx = boff[b] + woff + texcl;
#pragma unroll
    for (int j = 0; j < 4; ++j) {
        int i = base + j;
        if (i < N_NODES) rowptr[i] = pfx;
        else if (i == N_NODES) rowptr[i] = pfx;
        pfx += d[j];
    }
}

// ---------------- scatter: sorted-by-dst src index ONLY (4 B/edge) -------
// slot = rowptr[d] + rank[e]  -> atomic-free. Weights recomputed in agg.
__global__ __launch_bounds__(256) void k_scatter(
    const int* __restrict__ src, const int* __restrict__ dst,
    const int* __restrict__ rank, const int* __restrict__ rowptr,
    int* __restrict__ srcs) {
    int e = blockIdx.x * blockDim.x + threadIdx.x;
    if (e >= N_EDGES) return;
    int d = dst[e];
    srcs[rowptr[d] + rank[e]] = src[e];
}

// ---------------- CSR gather-aggregate (single pass) ----------------------
// One 64-lane wave per dst node. lane = (grp=edge-parity)<<5 | cl.
// cl covers channels cl*4..cl*4+3 (half4 = 8 B load). Per-edge weight
// w = exp(lrelu(el[src]+er[dst])) computed in-register (er hoisted).
// Unnormalized accumulate + denominator in one pass; scale at the end.
__global__ __launch_bounds__(256) void k_agg_csr(
    const int* __restrict__ rowptr, const int* __restrict__ srcs,
    const float* __restrict__ el, const float* __restrict__ er,
    const __half* __restrict__ hhalf, float* __restrict__ out) {
    int node = blockIdx.x * 4 + (threadIdx.x >> 6);
    int lane = threadIdx.x & 63;
    int grp = lane >> 5;
    int cl = lane & 31;
    int head = cl >> 3;
    int beg = rowptr[node], end = rowptr[node + 1];

    const float er_h = er[(size_t)node * NH + head];

    float dsum = 0.0f;
    float a0 = 0.0f, a1 = 0.0f, a2 = 0.0f, a3 = 0.0f;

    int i = beg + grp;
    for (; i + 2 < end; i += 4) {
        int s0 = srcs[i];
        int s1 = srcs[i + 2];
        float w0 = __expf(lrelu(el[(size_t)s0 * NH + head] + er_h));
        float w1 = __expf(lrelu(el[(size_t)s1 * NH + head] + er_h));
        Pack8 p0, p1;
        p0.u = *(const uint2*)(hhalf + (size_t)s0 * HD + cl * 4);
        p1.u = *(const uint2*)(hhalf + (size_t)s1 * HD + cl * 4);
        dsum += w0 + w1;
        float2 x0 = __half22float2(p0.h2[0]), y0 = __half22float2(p0.h2[1]);
        float2 x1 = __half22float2(p1.h2[0]), y1 = __half22float2(p1.h2[1]);
        a0 = fmaf(x0.x, w0, a0); a1 = fmaf(x0.y, w0, a1);
        a2 = fmaf(y0.x, w0, a2); a3 = fmaf(y0.y, w0, a3);
        a0 = fmaf(x1.x, w1, a0); a1 = fmaf(x1.y, w1, a1);
        a2 = fmaf(y1.x, w1, a2); a3 = fmaf(y1.y, w1, a3);
    }
    if (i < end) {
        int s0 = srcs[i];
        float w0 = __expf(lrelu(el[(size_t)s0 * NH + head] + er_h));
        Pack8 p0;
        p0.u = *(const uint2*)(hhalf + (size_t)s0 * HD + cl * 4);
        dsum += w0;
        float2 x0 = __half22float2(p0.h2[0]), y0 = __half22float2(p0.h2[1]);
        a0 = fmaf(x0.x, w0, a0); a1 = fmaf(x0.y, w0, a1);
        a2 = fmaf(y0.x, w0, a2); a3 = fmaf(y0.y, w0, a3);
    }

    dsum += __shfl_xor(dsum, 32, 64);
    a0 += __shfl_xor(a0, 32, 64);
    a1 += __shfl_xor(a1, 32, 64);
    a2 += __shfl_xor(a2, 32, 64);
    a3 += __shfl_xor(a3, 32, 64);

    if (grp == 0) {
        float inv = (end > beg) ? 1.0f / dsum : 0.0f;
        *(float4*)(out + (size_t)node * HD + cl * 4) =
            make_float4(a0 * inv, a1 * inv, a2 * inv, a3 * inv);
    }
}

// ---------------- fallback path (atomics) --------------------------------
__global__ __launch_bounds__(256) void k_denom_fb(
    const int* __restrict__ src, const int* __restrict__ dst,
    const float* __restrict__ el, const float* __restrict__ er,
    float* __restrict__ denom) {
    int e = blockIdx.x * blockDim.x + threadIdx.x;
    if (e >= N_EDGES) return;
    int s = src[e], d = dst[e];
    float4 l = *(const float4*)(el + (size_t)s * NH);
    float4 r = *(const float4*)(er + (size_t)d * NH);
    float* dn = denom + (size_t)d * NH;
    atomicAdd(dn + 0, __expf(lrelu(l.x + r.x)));
    atomicAdd(dn + 1, __expf(lrelu(l.y + r.y)));
    atomicAdd(dn + 2, __expf(lrelu(l.z + r.z)));
    atomicAdd(dn + 3, __expf(lrelu(l.w + r.w)));
}

__global__ __launch_bounds__(256) void k_agg_fb(
    const int* __restrict__ src, const int* __restrict__ dst,
    const float* __restrict__ el, const float* __restrict__ er,
    const float* __restrict__ denom, const __half* __restrict__ hhalf,
    float* __restrict__ out) {
    long long t = (long long)blockIdx.x * blockDim.x + threadIdx.x;
    if (t >= (long long)N_EDGES * HD) return;
    int e = (int)(t >> 7);
    int c = (int)(t & 127);
    int hh = c >> 5;
    int s = src[e], d = dst[e];
    float x = lrelu(el[(size_t)s * NH + hh] + er[(size_t)d * NH + hh]);
    float a = __expf(x) / denom[(size_t)d * NH + hh];
    atomicAdd(out + (size_t)d * HD + c,
              __half2float(hhalf[(size_t)s * HD + c]) * a);
}

extern "C" void kernel_launch(void* const* d_in, const int* in_sizes, int n_in,
                              void* d_out, int out_size, void* d_ws, size_t ws_size,
                              hipStream_t stream) {
    const float* feat   = (const float*)d_in[0];
    const int*   src    = (const int*)d_in[1];
    const int*   dst    = (const int*)d_in[2];
    const float* W      = (const float*)d_in[3];
    const float* attn_l = (const float*)d_in[4];
    const float* attn_r = (const float*)d_in[5];
    float* out = (float*)d_out;

    char* base = (char*)d_ws;
    size_t off = 0;
    auto take = [&](size_t bytes) -> char* {
        char* r = base + off;
        off = (off + bytes + 255) & ~(size_t)255;
        return r;
    };
    __half* hhalf = (__half*)take((size_t)N_NODES * HD * 2);
    float* el     = (float*)take((size_t)N_NODES * NH * 4);
    float* er     = (float*)take((size_t)N_NODES * NH * 4);
    int*   deg    = (int*)take((size_t)N_NODES * 4);
    int*   rowptr = (int*)take((size_t)(N_NODES + 1) * 4);
    int*   rank   = (int*)take((size_t)N_EDGES * 4);
    int*   bsum   = (int*)take(SCAN_NB * 4);
    int*   boff   = (int*)take(SCAN_NB * 4);
    int*   srcs   = (int*)take((size_t)N_EDGES * 4);
    float* denom  = (float*)take((size_t)N_NODES * NH * 4); // fallback only
    bool csr = (off <= ws_size);

    int eb = (N_EDGES + 255) / 256;

    if (csr) {
        k_init<<<128, 256, 0, stream>>>(deg);
        k_gemm<<<N_NODES / GROWS, 256, 0, stream>>>(feat, W, attn_l, attn_r,
                                                    hhalf, el, er);
        k_count<<<eb, 256, 0, stream>>>(dst, deg, rank);
        k_scanA<<<SCAN_NB, 256, 0, stream>>>(deg, bsum);
        k_scanB<<<1, 128, 0, stream>>>(bsum, boff);
        k_scanC<<<SCAN_NB, 256, 0, stream>>>(deg, boff, rowptr);
        k_scatter<<<eb, 256, 0, stream>>>(src, dst, rank, rowptr, srcs);
        k_agg_csr<<<N_NODES / 4, 256, 0, stream>>>(rowptr, srcs, el, er, hhalf, out);
    } else {
        k_init_fb<<<2048, 256, 0, stream>>>(out, denom);
        k_gemm<<<N_NODES / GROWS, 256, 0, stream>>>(feat, W, attn_l, attn_r,
                                                    hhalf, el, er);
        k_denom_fb<<<eb, 256, 0, stream>>>(src, dst, el, er, denom);
        long long tot = (long long)N_EDGES * HD;
        int ab = (int)((tot + 255) / 256);
        k_agg_fb<<<ab, 256, 0, stream>>>(src, dst, el, er, denom, hhalf, out);
    }
}

// Round 7
// 199.912 us; speedup vs baseline: 7.1879x; 1.1820x over previous
//
#include <hip/hip_runtime.h>
#include <hip/hip_fp16.h>

#define N_NODES 100000
#define N_EDGES 1600000
#define DIN 128
#define NH 4
#define ND 32
#define HD 128   // NH*ND
#define NEG_SLOPE 0.2f
#define SCAN_NB 98   // ceil(N_NODES / 1024)
#define GROWS 32
#define GEMM_BLOCKS (N_NODES / GROWS)            // 3125
#define EDGES_PER_BLOCK (N_EDGES / GEMM_BLOCKS)  // 512 exactly

__device__ __forceinline__ float lrelu(float x) {
    return x > 0.0f ? x : NEG_SLOPE * x;
}

union Pack8  { uint2 u; __half2 h2[2]; };
union Pack16 { uint4 u; __half2 h2[4]; };

// ---------------- init: zero deg ------------------------------------------
__global__ void k_init(int* __restrict__ deg) {
    int i = blockIdx.x * blockDim.x + threadIdx.x;
    int stride = gridDim.x * blockDim.x;
    for (int j = i; j < N_NODES; j += stride) deg[j] = 0;
}

// ---------------- init (fallback path): zero out + denom ------------------
__global__ void k_init_fb(float* __restrict__ out, float* __restrict__ denom) {
    int i = blockIdx.x * blockDim.x + threadIdx.x;
    int stride = gridDim.x * blockDim.x;
    for (int j = i; j < N_NODES * HD; j += stride) out[j] = 0.0f;
    for (int j = i; j < N_NODES * NH; j += stride) denom[j] = 0.0f;
}

// ---------------- GEMM h = feat @ W (fp16 out), fused el/er + edge count --
// block 256 threads, tile 32 rows x 128 cols, thread = 4 rows x 4 cols.
// Tail: each block counts its 512-edge chunk (rank = atomicAdd on deg),
// hiding atomic latency under other waves' FMA work.
__global__ __launch_bounds__(256) void k_gemm(
    const float* __restrict__ feat, const float* __restrict__ W,
    const float* __restrict__ attn_l, const float* __restrict__ attn_r,
    __half* __restrict__ hhalf, float* __restrict__ el, float* __restrict__ er,
    const int* __restrict__ dst, int* __restrict__ deg, int* __restrict__ rank) {

    __shared__ float Ws[DIN * HD];      // 64 KB, [k][c]
    __shared__ float fs[GROWS * DIN];   // 16 KB, [r][k]

    const int tid = threadIdx.x;
    const int row0 = blockIdx.x * GROWS;

    {   // stage W: 4096 float4
        const float4* Wv = (const float4*)W;
        float4* Sv = (float4*)Ws;
#pragma unroll
        for (int it = 0; it < 16; ++it) Sv[tid + it * 256] = Wv[tid + it * 256];
    }
    {   // stage 32 feat rows: 1024 float4
        const float4* Fv = (const float4*)(feat + (size_t)row0 * DIN);
        float4* Sv = (float4*)fs;
#pragma unroll
        for (int it = 0; it < 4; ++it) Sv[tid + it * 256] = Fv[tid + it * 256];
    }
    __syncthreads();

    const int cg = tid & 31;   // cols 4*cg .. 4*cg+3
    const int rg = tid >> 5;   // rows 4*rg .. 4*rg+3

    float acc[4][4];
#pragma unroll
    for (int r = 0; r < 4; ++r)
#pragma unroll
        for (int c = 0; c < 4; ++c) acc[r][c] = 0.0f;

    for (int k = 0; k < DIN; k += 4) {
        float4 f0 = *(const float4*)&fs[(rg * 4 + 0) * DIN + k];
        float4 f1 = *(const float4*)&fs[(rg * 4 + 1) * DIN + k];
        float4 f2 = *(const float4*)&fs[(rg * 4 + 2) * DIN + k];
        float4 f3 = *(const float4*)&fs[(rg * 4 + 3) * DIN + k];
        const float* fp0 = (const float*)&f0;
        const float* fp1 = (const float*)&f1;
        const float* fp2 = (const float*)&f2;
        const float* fp3 = (const float*)&f3;
#pragma unroll
        for (int kk = 0; kk < 4; ++kk) {
            float4 w = *(const float4*)&Ws[(k + kk) * HD + cg * 4];
            float b0 = fp0[kk], b1 = fp1[kk], b2 = fp2[kk], b3 = fp3[kk];
            acc[0][0] = fmaf(b0, w.x, acc[0][0]);
            acc[0][1] = fmaf(b0, w.y, acc[0][1]);
            acc[0][2] = fmaf(b0, w.z, acc[0][2]);
            acc[0][3] = fmaf(b0, w.w, acc[0][3]);
            acc[1][0] = fmaf(b1, w.x, acc[1][0]);
            acc[1][1] = fmaf(b1, w.y, acc[1][1]);
            acc[1][2] = fmaf(b1, w.z, acc[1][2]);
            acc[1][3] = fmaf(b1, w.w, acc[1][3]);
            acc[2][0] = fmaf(b2, w.x, acc[2][0]);
            acc[2][1] = fmaf(b2, w.y, acc[2][1]);
            acc[2][2] = fmaf(b2, w.z, acc[2][2]);
            acc[2][3] = fmaf(b2, w.w, acc[2][3]);
            acc[3][0] = fmaf(b3, w.x, acc[3][0]);
            acc[3][1] = fmaf(b3, w.y, acc[3][1]);
            acc[3][2] = fmaf(b3, w.z, acc[3][2]);
            acc[3][3] = fmaf(b3, w.w, acc[3][3]);
        }
    }

    const float4 alv = *(const float4*)(attn_l + cg * 4);
    const float4 arv = *(const float4*)(attn_r + cg * 4);
    const int head = cg >> 3;

#pragma unroll
    for (int r = 0; r < 4; ++r) {
        int row = row0 + rg * 4 + r;
        Pack8 pk;
        pk.h2[0] = __floats2half2_rn(acc[r][0], acc[r][1]);
        pk.h2[1] = __floats2half2_rn(acc[r][2], acc[r][3]);
        *(uint2*)(hhalf + (size_t)row * HD + cg * 4) = pk.u;
        float vl = acc[r][0] * alv.x + acc[r][1] * alv.y +
                   acc[r][2] * alv.z + acc[r][3] * alv.w;
        float vr = acc[r][0] * arv.x + acc[r][1] * arv.y +
                   acc[r][2] * arv.z + acc[r][3] * arv.w;
        vl += __shfl_down(vl, 4, 64);
        vl += __shfl_down(vl, 2, 64);
        vl += __shfl_down(vl, 1, 64);
        vr += __shfl_down(vr, 4, 64);
        vr += __shfl_down(vr, 2, 64);
        vr += __shfl_down(vr, 1, 64);
        if ((cg & 7) == 0) {
            el[(size_t)row * NH + head] = vl;
            er[(size_t)row * NH + head] = vr;
        }
    }

    // ---- fused edge count: this block's 512-edge chunk, 2 per thread ----
    if (deg) {
        int e0 = blockIdx.x * EDGES_PER_BLOCK + tid * 2;
#pragma unroll
        for (int j = 0; j < 2; ++j) {
            int e = e0 + j;
            if (e < N_EDGES) rank[e] = atomicAdd(deg + dst[e], 1);
        }
    }
}

// ---------------- scan: deg -> rowptr (exclusive) ------------------------
__global__ __launch_bounds__(256) void k_scanA(const int* __restrict__ deg,
                                               int* __restrict__ bsum) {
    __shared__ int wsum[4];
    int b = blockIdx.x, tid = threadIdx.x;
    int base = b * 1024 + tid * 4;
    int s = 0;
#pragma unroll
    for (int j = 0; j < 4; ++j) {
        int i = base + j;
        if (i < N_NODES) s += deg[i];
    }
#pragma unroll
    for (int off = 32; off >= 1; off >>= 1) s += __shfl_down(s, off, 64);
    if ((tid & 63) == 0) wsum[tid >> 6] = s;
    __syncthreads();
    if (tid == 0) bsum[b] = wsum[0] + wsum[1] + wsum[2] + wsum[3];
}

__global__ __launch_bounds__(128) void k_scanB(const int* __restrict__ bsum,
                                               int* __restrict__ boff) {
    __shared__ int tmp[SCAN_NB];
    int tid = threadIdx.x;
    if (tid < SCAN_NB) tmp[tid] = bsum[tid];
    __syncthreads();
    if (tid == 0) {
        int acc = 0;
        for (int i = 0; i < SCAN_NB; ++i) { int v = tmp[i]; tmp[i] = acc; acc += v; }
    }
    __syncthreads();
    if (tid < SCAN_NB) boff[tid] = tmp[tid];
}

__global__ __launch_bounds__(256) void k_scanC(const int* __restrict__ deg,
                                               const int* __restrict__ boff,
                                               int* __restrict__ rowptr) {
    __shared__ int wtot[4];
    int b = blockIdx.x, tid = threadIdx.x;
    int base = b * 1024 + tid * 4;
    int d[4];
#pragma unroll
    for (int j = 0; j < 4; ++j) {
        int i = base + j;
        d[j] = (i < N_NODES) ? deg[i] : 0;
    }
    int tsum = d[0] + d[1] + d[2] + d[3];
    int lane = tid & 63;
    int v = tsum;
#pragma unroll
    for (int off = 1; off < 64; off <<= 1) {
        int t = __shfl_up(v, off, 64);
        if (lane >= off) v += t;
    }
    if (lane == 63) wtot[tid >> 6] = v;
    int texcl = v - tsum;
    __syncthreads();
    int woff = 0;
    for (int w = 0; w < (tid >> 6); ++w) woff += wtot[w];
    int pfx = boff[b] + woff + texcl;
#pragma unroll
    for (int j = 0; j < 4; ++j) {
        int i = base + j;
        if (i < N_NODES) rowptr[i] = pfx;
        else if (i == N_NODES) rowptr[i] = pfx;
        pfx += d[j];
    }
}

// ---------------- scatter: sorted-by-dst src index ONLY (4 B/edge) -------
__global__ __launch_bounds__(256) void k_scatter(
    const int* __restrict__ src, const int* __restrict__ dst,
    const int* __restrict__ rank, const int* __restrict__ rowptr,
    int* __restrict__ srcs) {
    int e = blockIdx.x * blockDim.x + threadIdx.x;
    if (e >= N_EDGES) return;
    int d = dst[e];
    srcs[rowptr[d] + rank[e]] = src[e];
}

// ---------------- CSR gather-aggregate (single pass) ----------------------
// One 64-lane wave per dst node. lane = grp<<4 | cl; grp = 4-way edge
// parallelism, cl covers channels cl*8..cl*8+7 (half8 = 16 B load).
// Per-edge weight recomputed in-register (er hoisted). Unnormalized
// accumulate + denominator in one pass; 2-level shfl_xor reduce; scale at end.
__global__ __launch_bounds__(256) void k_agg_csr(
    const int* __restrict__ rowptr, const int* __restrict__ srcs,
    const float* __restrict__ el, const float* __restrict__ er,
    const __half* __restrict__ hhalf, float* __restrict__ out) {
    int node = blockIdx.x * 4 + (threadIdx.x >> 6);
    int lane = threadIdx.x & 63;
    int grp = lane >> 4;        // 0..3: edge parity
    int cl = lane & 15;         // channels cl*8 .. cl*8+7
    int head = cl >> 2;
    int beg = rowptr[node], end = rowptr[node + 1];

    const float er_h = er[(size_t)node * NH + head];

    float dsum = 0.0f;
    float a[8];
#pragma unroll
    for (int q = 0; q < 8; ++q) a[q] = 0.0f;

    int i = beg + grp;
    for (; i + 4 < end; i += 8) {
        int s0 = srcs[i];
        int s1 = srcs[i + 4];
        float w0 = __expf(lrelu(el[(size_t)s0 * NH + head] + er_h));
        float w1 = __expf(lrelu(el[(size_t)s1 * NH + head] + er_h));
        Pack16 p0, p1;
        p0.u = *(const uint4*)(hhalf + (size_t)s0 * HD + cl * 8);
        p1.u = *(const uint4*)(hhalf + (size_t)s1 * HD + cl * 8);
        dsum += w0 + w1;
#pragma unroll
        for (int q = 0; q < 4; ++q) {
            float2 x0 = __half22float2(p0.h2[q]);
            float2 x1 = __half22float2(p1.h2[q]);
            a[2 * q]     = fmaf(x0.x, w0, a[2 * q]);
            a[2 * q + 1] = fmaf(x0.y, w0, a[2 * q + 1]);
            a[2 * q]     = fmaf(x1.x, w1, a[2 * q]);
            a[2 * q + 1] = fmaf(x1.y, w1, a[2 * q + 1]);
        }
    }
    if (i < end) {
        int s0 = srcs[i];
        float w0 = __expf(lrelu(el[(size_t)s0 * NH + head] + er_h));
        Pack16 p0;
        p0.u = *(const uint4*)(hhalf + (size_t)s0 * HD + cl * 8);
        dsum += w0;
#pragma unroll
        for (int q = 0; q < 4; ++q) {
            float2 x0 = __half22float2(p0.h2[q]);
            a[2 * q]     = fmaf(x0.x, w0, a[2 * q]);
            a[2 * q + 1] = fmaf(x0.y, w0, a[2 * q + 1]);
        }
    }

    dsum += __shfl_xor(dsum, 16, 64);
    dsum += __shfl_xor(dsum, 32, 64);
#pragma unroll
    for (int q = 0; q < 8; ++q) {
        a[q] += __shfl_xor(a[q], 16, 64);
        a[q] += __shfl_xor(a[q], 32, 64);
    }

    if (grp == 0) {
        float inv = (end > beg) ? 1.0f / dsum : 0.0f;
        *(float4*)(out + (size_t)node * HD + cl * 8) =
            make_float4(a[0] * inv, a[1] * inv, a[2] * inv, a[3] * inv);
        *(float4*)(out + (size_t)node * HD + cl * 8 + 4) =
            make_float4(a[4] * inv, a[5] * inv, a[6] * inv, a[7] * inv);
    }
}

// ---------------- fallback path (atomics) --------------------------------
__global__ __launch_bounds__(256) void k_denom_fb(
    const int* __restrict__ src, const int* __restrict__ dst,
    const float* __restrict__ el, const float* __restrict__ er,
    float* __restrict__ denom) {
    int e = blockIdx.x * blockDim.x + threadIdx.x;
    if (e >= N_EDGES) return;
    int s = src[e], d = dst[e];
    float4 l = *(const float4*)(el + (size_t)s * NH);
    float4 r = *(const float4*)(er + (size_t)d * NH);
    float* dn = denom + (size_t)d * NH;
    atomicAdd(dn + 0, __expf(lrelu(l.x + r.x)));
    atomicAdd(dn + 1, __expf(lrelu(l.y + r.y)));
    atomicAdd(dn + 2, __expf(lrelu(l.z + r.z)));
    atomicAdd(dn + 3, __expf(lrelu(l.w + r.w)));
}

__global__ __launch_bounds__(256) void k_agg_fb(
    const int* __restrict__ src, const int* __restrict__ dst,
    const float* __restrict__ el, const float* __restrict__ er,
    const float* __restrict__ denom, const __half* __restrict__ hhalf,
    float* __restrict__ out) {
    long long t = (long long)blockIdx.x * blockDim.x + threadIdx.x;
    if (t >= (long long)N_EDGES * HD) return;
    int e = (int)(t >> 7);
    int c = (int)(t & 127);
    int hh = c >> 5;
    int s = src[e], d = dst[e];
    float x = lrelu(el[(size_t)s * NH + hh] + er[(size_t)d * NH + hh]);
    float a = __expf(x) / denom[(size_t)d * NH + hh];
    atomicAdd(out + (size_t)d * HD + c,
              __half2float(hhalf[(size_t)s * HD + c]) * a);
}

extern "C" void kernel_launch(void* const* d_in, const int* in_sizes, int n_in,
                              void* d_out, int out_size, void* d_ws, size_t ws_size,
                              hipStream_t stream) {
    const float* feat   = (const float*)d_in[0];
    const int*   src    = (const int*)d_in[1];
    const int*   dst    = (const int*)d_in[2];
    const float* W      = (const float*)d_in[3];
    const float* attn_l = (const float*)d_in[4];
    const float* attn_r = (const float*)d_in[5];
    float* out = (float*)d_out;

    char* base = (char*)d_ws;
    size_t off = 0;
    auto take = [&](size_t bytes) -> char* {
        char* r = base + off;
        off = (off + bytes + 255) & ~(size_t)255;
        return r;
    };
    __half* hhalf = (__half*)take((size_t)N_NODES * HD * 2);
    float* el     = (float*)take((size_t)N_NODES * NH * 4);
    float* er     = (float*)take((size_t)N_NODES * NH * 4);
    int*   deg    = (int*)take((size_t)N_NODES * 4);
    int*   rowptr = (int*)take((size_t)(N_NODES + 1) * 4);
    int*   rank   = (int*)take((size_t)N_EDGES * 4);
    int*   bsum   = (int*)take(SCAN_NB * 4);
    int*   boff   = (int*)take(SCAN_NB * 4);
    int*   srcs   = (int*)take((size_t)N_EDGES * 4);
    float* denom  = (float*)take((size_t)N_NODES * NH * 4); // fallback only
    bool csr = (off <= ws_size);

    int eb = (N_EDGES + 255) / 256;

    if (csr) {
        k_init<<<128, 256, 0, stream>>>(deg);
        k_gemm<<<GEMM_BLOCKS, 256, 0, stream>>>(feat, W, attn_l, attn_r,
                                                hhalf, el, er, dst, deg, rank);
        k_scanA<<<SCAN_NB, 256, 0, stream>>>(deg, bsum);
        k_scanB<<<1, 128, 0, stream>>>(bsum, boff);
        k_scanC<<<SCAN_NB, 256, 0, stream>>>(deg, boff, rowptr);
        k_scatter<<<eb, 256, 0, stream>>>(src, dst, rank, rowptr, srcs);
        k_agg_csr<<<N_NODES / 4, 256, 0, stream>>>(rowptr, srcs, el, er, hhalf, out);
    } else {
        k_init_fb<<<2048, 256, 0, stream>>>(out, denom);
        k_gemm<<<GEMM_BLOCKS, 256, 0, stream>>>(feat, W, attn_l, attn_r,
                                                hhalf, el, er, dst,
                                                (int*)nullptr, (int*)nullptr);
        k_denom_fb<<<eb, 256, 0, stream>>>(src, dst, el, er, denom);
        long long tot = (long long)N_EDGES * HD;
        int ab = (int)((tot + 255) / 256);
        k_agg_fb<<<ab, 256, 0, stream>>>(src, dst, el, er, denom, hhalf, out);
    }
}